// Round 2
// baseline (1051.891 us; speedup 1.0000x reference)
//
#include <hip/hip_runtime.h>

// LinearTransformerBlock on MI355X.
// Dtype (round-2 forensics): buffers are FP32 (per harness contract: reference
// dtype float32 -> const float*), but input VALUES are bf16-rounded by the
// harness (test label "(bf16, ref=np)", floor_eps_k=8). Round-1's bf16-bits
// reinterpretation produced NaN exactly as an fp32 buffer would (low-half u16s
// hit exponent 0xFF). So: read fp32, pack to bf16 at LDS staging (lossless on
// bf16-rounded values), fp32 output.

typedef unsigned short u16;
typedef __attribute__((ext_vector_type(8))) short bf16x8;   // 8 bf16 = 4 VGPRs
typedef __attribute__((ext_vector_type(4))) float f32x4;

__device__ __forceinline__ float bf2f(u16 u) {
    union { unsigned int i; float f; } x; x.i = ((unsigned int)u) << 16; return x.f;
}
__device__ __forceinline__ u16 f2bf(float f) {
    union { unsigned int i; float f; } x; x.f = f;
    unsigned int i = x.i;
    return (u16)((i + 0x7fffu + ((i >> 16) & 1u)) >> 16);   // RNE
}
// pack 8 consecutive fp32 -> 8 bf16 (uint4)
__device__ __forceinline__ uint4 pack8(const float* __restrict__ src) {
    float4 f0 = *(const float4*)(src);
    float4 f1 = *(const float4*)(src + 4);
    union { u16 u[8]; uint4 v; } P;
    P.u[0] = f2bf(f0.x); P.u[1] = f2bf(f0.y); P.u[2] = f2bf(f0.z); P.u[3] = f2bf(f0.w);
    P.u[4] = f2bf(f1.x); P.u[5] = f2bf(f1.y); P.u[6] = f2bf(f1.z); P.u[7] = f2bf(f1.w);
    return P.v;
}

// ---------------------------------------------------------------------------
// Kernel 1: fused QKV projection + bias + RoPE + ReLU.
// C = X[8192,2048] @ W^T, W in {Wq,Wk,Wv} picked per 128-col block region.
// bf16 MFMA 16x16x32, 128x128 block tile, BK=32, 4 waves each 64x64.
// Output layout: [B,H,S,D] bf16 (per-(b,h) contiguous S x D).
// ---------------------------------------------------------------------------
__global__ __launch_bounds__(256) void gemm_qkv(
    const float* __restrict__ X,
    const float* __restrict__ Wq, const float* __restrict__ Wk, const float* __restrict__ Wv,
    const float* __restrict__ bq, const float* __restrict__ bk, const float* __restrict__ bv,
    const float* __restrict__ cosT, const float* __restrict__ sinT,
    u16* __restrict__ Q, u16* __restrict__ K, u16* __restrict__ V)
{
    const int Kd = 2048;
    __shared__ __align__(16) u16 As[128 * 32];
    __shared__ __align__(16) u16 Bs[128 * 32];

    int t  = threadIdx.x;
    int bm = blockIdx.x;          // 0..63  (M tiles)
    int bn = blockIdx.y;          // 0..47  (N tiles across q|k|v)
    int region = bn >> 4;         // 0=q, 1=k, 2=v (uniform per block)
    const float* W    = (region == 0) ? Wq : (region == 1 ? Wk : Wv);
    const float* bias = (region == 0) ? bq : (region == 1 ? bk : bv);
    u16* OUT          = (region == 0) ? Q  : (region == 1 ? K  : V);

    int m0 = bm * 128;
    int n0 = (bn & 15) * 128;     // col offset within the region's 2048

    int w = t >> 6, lane = t & 63, quad = lane >> 4, l16 = lane & 15;
    int wm0 = (w >> 1) * 64, wn0 = (w & 1) * 64;

    int arow = t >> 2;            // 0..63
    int acol = (t & 3) * 8;       // element col within BK

    f32x4 acc[4][4] = {};

    for (int k0 = 0; k0 < Kd; k0 += 32) {
        __syncthreads();
        *(uint4*)((char*)As + t * 16)        = pack8(X + (size_t)(m0 + arow) * Kd      + k0 + acol);
        *(uint4*)((char*)As + 4096 + t * 16) = pack8(X + (size_t)(m0 + arow + 64) * Kd + k0 + acol);
        *(uint4*)((char*)Bs + t * 16)        = pack8(W + (size_t)(n0 + arow) * Kd      + k0 + acol);
        *(uint4*)((char*)Bs + 4096 + t * 16) = pack8(W + (size_t)(n0 + arow + 64) * Kd + k0 + acol);
        __syncthreads();

        bf16x8 af[4], bfr[4];
#pragma unroll
        for (int i = 0; i < 4; i++) af[i]  = *(const bf16x8*)(As + (wm0 + i * 16 + l16) * 32 + quad * 8);
#pragma unroll
        for (int j = 0; j < 4; j++) bfr[j] = *(const bf16x8*)(Bs + (wn0 + j * 16 + l16) * 32 + quad * 8);
#pragma unroll
        for (int i = 0; i < 4; i++)
#pragma unroll
            for (int j = 0; j < 4; j++)
                acc[i][j] = __builtin_amdgcn_mfma_f32_16x16x32_bf16(af[i], bfr[j], acc[i][j], 0, 0, 0);
    }

    // Epilogue: bias, then RoPE (+pair via shfl_xor 1: col == lane&15), ReLU (q,k only).
#pragma unroll
    for (int i = 0; i < 4; i++) {
#pragma unroll
        for (int j = 0; j < 4; j++) {
            int nc   = n0 + wn0 + j * 16 + l16;   // 0..2047 within region
            int h    = nc >> 7, dpos = nc & 127;
            float bia = bias[nc];
#pragma unroll
            for (int r = 0; r < 4; r++) {
                int mr = m0 + wm0 + i * 16 + quad * 4 + r;   // C/D: row = quad*4+reg
                int b  = mr >> 12, s = mr & 4095;
                float val = acc[i][j][r] + bia;
                if (region < 2) {
                    float pair = __shfl_xor(val, 1, 64);     // paired dim (bias included)
                    float c  = cosT[s * 128 + dpos];
                    float sn = sinT[s * 128 + dpos];
                    val = fmaxf(val * c + ((dpos & 1) ? pair : -pair) * sn, 0.f);
                }
                OUT[((size_t)(b * 16 + h) * 4096 + s) * 128 + dpos] = f2bf(val);
            }
        }
    }
}

// ---------------------------------------------------------------------------
// Kernel 2: vk partials. Per (b,h), split S into 8 chunks of 512 rows.
// vk[n,d] = sum_s v_pad[s,n] * k[s,d];  pad row (n=128) = sum_s k[s,d].
// Thread grid 16(n) x 16(d), 8x8 accumulators in registers, k/v rows via LDS.
// K/V here are our bf16 intermediates.
// ---------------------------------------------------------------------------
__global__ __launch_bounds__(256) void vk_partial(
    const u16* __restrict__ Kb, const u16* __restrict__ Vb, float* __restrict__ part)
{
    int bh = blockIdx.x;          // 0..31
    int sp = blockIdx.y;          // 0..7
    int t  = threadIdx.x;
    int tn = t >> 4, td = t & 15;
    int n0 = tn * 8, d0 = td * 8;
    const u16* Kp = Kb + (size_t)bh * 4096 * 128;
    const u16* Vp = Vb + (size_t)bh * 4096 * 128;
    int s0 = sp * 512;

    __shared__ __align__(16) u16 ks[8 * 128];
    __shared__ __align__(16) u16 vs[8 * 128];

    float acc[8][8] = {};
    float ksum[8] = {};

    for (int sc = 0; sc < 512; sc += 8) {
        __syncthreads();
        {
            int tt   = t & 127;
            int row  = tt >> 4;
            int cole = (tt & 15) * 8;            // element offset within row
            const u16* srcp = (t < 128) ? Kp : Vp;
            u16*       dstp = (t < 128) ? ks : vs;
            const u16* src = srcp + (size_t)(s0 + sc + row) * 128 + cole;
            *(uint4*)((char*)dstp + tt * 16) = *(const uint4*)src;
        }
        __syncthreads();
#pragma unroll
        for (int ss = 0; ss < 8; ss++) {
            float vv[8], kv[8];
#pragma unroll
            for (int j = 0; j < 8; j++) vv[j] = bf2f(vs[ss * 128 + n0 + j]);
#pragma unroll
            for (int j = 0; j < 8; j++) kv[j] = bf2f(ks[ss * 128 + d0 + j]);
#pragma unroll
            for (int i = 0; i < 8; i++)
#pragma unroll
                for (int j = 0; j < 8; j++) acc[i][j] += vv[i] * kv[j];
            if (tn == 0) {
#pragma unroll
                for (int j = 0; j < 8; j++) ksum[j] += kv[j];
            }
        }
    }

    float* dst = part + (size_t)(bh * 8 + sp) * 16512;   // 129*128
#pragma unroll
    for (int i = 0; i < 8; i++)
#pragma unroll
        for (int j = 0; j < 8; j++) dst[(n0 + i) * 128 + d0 + j] = acc[i][j];
    if (tn == 0) {
#pragma unroll
        for (int j = 0; j < 8; j++) dst[16384 + d0 + j] = ksum[j];
    }
}

// ---------------------------------------------------------------------------
// Kernel 3: reduce 8 partials -> vk_final[32][129*128] fp32.
// ---------------------------------------------------------------------------
__global__ __launch_bounds__(256) void vk_reduce(const float* __restrict__ part,
                                                 float* __restrict__ vkf)
{
    int bh = blockIdx.x;          // 0..31
    int by = blockIdx.y;          // 0..7
    int t  = threadIdx.x;
    int end = (by + 1) * 2064;    // 16512/8
    for (int idx = by * 2064 + t; idx < end; idx += 256) {
        float s = 0.f;
#pragma unroll
        for (int p = 0; p < 8; p++) s += part[(size_t)(bh * 8 + p) * 16512 + idx];
        vkf[(size_t)bh * 16512 + idx] = s;
    }
}

// ---------------------------------------------------------------------------
// Kernel 4: hs[s,n] = sum_d vk[n,d] q[s,d]; normalize by pad-row dot + EPS.
// Grid (bh, s-chunk of 128, n-half). vk half staged in LDS, rows padded to 129
// floats (stride 129 -> 2-way bank alias max = free).
// Writes hs bf16 in [B*S, 2048] at col h*128+n (reuses V's buffer).
// ---------------------------------------------------------------------------
__global__ __launch_bounds__(256) void hs_kernel(
    const u16* __restrict__ Qb, const float* __restrict__ vkf, u16* __restrict__ HS)
{
    int bh = blockIdx.x;          // 0..31
    int sc = blockIdx.y;          // 0..31
    int nh = blockIdx.z;          // 0..1
    int t  = threadIdx.x;

    __shared__ __align__(16) float vkL[64 * 129];
    __shared__ float vsum[128];
    __shared__ float rden[128];

    const float* vsrc = vkf + (size_t)bh * 16512;
    for (int idx = t; idx < 64 * 128; idx += 256) {
        int n = idx >> 7, d = idx & 127;
        vkL[n * 129 + d] = vsrc[(nh * 64 + n) * 128 + d];
    }
    if (t < 128) vsum[t] = vsrc[16384 + t];
    __syncthreads();

    const u16* Qp = Qb + ((size_t)bh * 4096 + sc * 128) * 128;

    // Phase A: denominators for the 128 s-rows (duplicated across nh blocks; cheap).
    {
        int srow = t >> 1, half = t & 1;
        const u16*  q    = Qp + srow * 128 + half * 64;
        const float* vs_ = vsum + half * 64;
        float p = 0.f;
#pragma unroll 8
        for (int d = 0; d < 64; d += 4) {
            ushort4 qv = *(const ushort4*)(q + d);
            p += bf2f(qv.x) * vs_[d] + bf2f(qv.y) * vs_[d + 1]
               + bf2f(qv.z) * vs_[d + 2] + bf2f(qv.w) * vs_[d + 3];
        }
        p += __shfl_xor(p, 1, 64);
        if (half == 0) rden[srow] = 1.0f / (p + 1e-15f);
    }
    __syncthreads();

    int nl = t & 63, ty = t >> 6;
    int b = bh >> 4, h = bh & 15;
    const float* vrow = vkL + nl * 129;
    int ncol = h * 128 + nh * 64 + nl;
    for (int sr = ty; sr < 128; sr += 4) {
        const u16* q = Qp + sr * 128;
        float dot = 0.f;
#pragma unroll 8
        for (int d = 0; d < 128; d += 4) {
            ushort4 qv = *(const ushort4*)(q + d);
            dot += bf2f(qv.x) * vrow[d] + bf2f(qv.y) * vrow[d + 1]
                 + bf2f(qv.z) * vrow[d + 2] + bf2f(qv.w) * vrow[d + 3];
        }
        size_t srow_g = (size_t)b * 4096 + sc * 128 + sr;
        HS[srow_g * 2048 + ncol] = f2bf(dot * rden[sr]);
    }
}

// ---------------------------------------------------------------------------
// Kernel 5: out = HS[8192,2048] @ Wo^T + bo  -> d_out fp32.
// A-side (HS) is bf16 intermediate; B-side (Wo) is fp32 -> packed at staging.
// ---------------------------------------------------------------------------
__global__ __launch_bounds__(256) void gemm_out(
    const u16* __restrict__ HSm, const float* __restrict__ Wo, const float* __restrict__ bo,
    float* __restrict__ OUT)
{
    const int Kd = 2048;
    __shared__ __align__(16) u16 As[128 * 32];
    __shared__ __align__(16) u16 Bs[128 * 32];

    int t  = threadIdx.x;
    int m0 = blockIdx.x * 128;    // 0..63
    int n0 = blockIdx.y * 128;    // 0..15

    int w = t >> 6, lane = t & 63, quad = lane >> 4, l16 = lane & 15;
    int wm0 = (w >> 1) * 64, wn0 = (w & 1) * 64;
    int arow = t >> 2;
    int acol = (t & 3) * 8;

    f32x4 acc[4][4] = {};

    for (int k0 = 0; k0 < Kd; k0 += 32) {
        __syncthreads();
        *(uint4*)((char*)As + t * 16)        = *(const uint4*)(HSm + (size_t)(m0 + arow) * Kd      + k0 + acol);
        *(uint4*)((char*)As + 4096 + t * 16) = *(const uint4*)(HSm + (size_t)(m0 + arow + 64) * Kd + k0 + acol);
        *(uint4*)((char*)Bs + t * 16)        = pack8(Wo + (size_t)(n0 + arow) * Kd      + k0 + acol);
        *(uint4*)((char*)Bs + 4096 + t * 16) = pack8(Wo + (size_t)(n0 + arow + 64) * Kd + k0 + acol);
        __syncthreads();

        bf16x8 af[4], bfr[4];
#pragma unroll
        for (int i = 0; i < 4; i++) af[i]  = *(const bf16x8*)(As + (wm0 + i * 16 + l16) * 32 + quad * 8);
#pragma unroll
        for (int j = 0; j < 4; j++) bfr[j] = *(const bf16x8*)(Bs + (wn0 + j * 16 + l16) * 32 + quad * 8);
#pragma unroll
        for (int i = 0; i < 4; i++)
#pragma unroll
            for (int j = 0; j < 4; j++)
                acc[i][j] = __builtin_amdgcn_mfma_f32_16x16x32_bf16(af[i], bfr[j], acc[i][j], 0, 0, 0);
    }

#pragma unroll
    for (int i = 0; i < 4; i++) {
#pragma unroll
        for (int j = 0; j < 4; j++) {
            int nc = n0 + wn0 + j * 16 + l16;
            float bia = bo[nc];
#pragma unroll
            for (int r = 0; r < 4; r++) {
                int mr = m0 + wm0 + i * 16 + quad * 4 + r;
                OUT[(size_t)mr * 2048 + nc] = acc[i][j][r] + bia;
            }
        }
    }
}

// ---------------------------------------------------------------------------
extern "C" void kernel_launch(void* const* d_in, const int* in_sizes, int n_in,
                              void* d_out, int out_size, void* d_ws, size_t ws_size,
                              hipStream_t stream) {
    const float* x    = (const float*)d_in[0];
    const float* cosT = (const float*)d_in[1];
    const float* sinT = (const float*)d_in[2];
    const float* Wq   = (const float*)d_in[3];
    const float* bq   = (const float*)d_in[4];
    const float* Wk   = (const float*)d_in[5];
    const float* bk   = (const float*)d_in[6];
    const float* Wv   = (const float*)d_in[7];
    const float* bv   = (const float*)d_in[8];
    const float* Wo   = (const float*)d_in[9];
    const float* bo   = (const float*)d_in[10];

    char* ws = (char*)d_ws;
    u16*   Q    = (u16*)(ws);                    // 33,554,432 B  bf16 [B,H,S,D]
    u16*   K    = (u16*)(ws + 33554432);         // 33,554,432 B
    u16*   V    = (u16*)(ws + 67108864);         // 33,554,432 B
    u16*   HS   = V;                             // V dead after vk_partial -> reuse
    float* part = (float*)(ws + 100663296);      // 256 * 16512 * 4 = 16,908,288 B
    float* vkf  = (float*)(ws + 117571584);      // 32 * 16512 * 4  =  2,113,536 B
    // total ws use: 119,685,120 B (~114 MB)

    gemm_qkv<<<dim3(64, 48), 256, 0, stream>>>(x, Wq, Wk, Wv, bq, bk, bv, cosT, sinT, Q, K, V);
    vk_partial<<<dim3(32, 8), 256, 0, stream>>>(K, V, part);
    vk_reduce<<<dim3(32, 8), 256, 0, stream>>>(part, vkf);
    hs_kernel<<<dim3(32, 32, 2), 256, 0, stream>>>(Q, vkf, HS);
    gemm_out<<<dim3(64, 16), 256, 0, stream>>>(HS, Wo, bo, (float*)d_out);
}

// Round 3
// 668.517 us; speedup vs baseline: 1.5735x; 1.5735x over previous
//
#include <hip/hip_runtime.h>

// LinearTransformerBlock on MI355X — R3.
// R2 passed (absmax 4.9e-4): fp32 buffers, bf16-rounded values. gemm_qkv was
// 378 TF, VALU-bound on pack8 staging (MfmaUtil 16.6 / VALUBusy 55).
// R3: pre-cast X/W to bf16 once; global_load_lds width-16 staging in both big
// GEMMs (m97 ladder step: 517->874 TF); hs stage MFMA-ized. Q/K scratch lives
// in d_out (dead before gemm_out overwrites it).

typedef unsigned short u16;
typedef __attribute__((ext_vector_type(8))) short bf16x8;   // 8 bf16 = 4 VGPRs
typedef __attribute__((ext_vector_type(4))) float f32x4;

__device__ __forceinline__ float bf2f(u16 u) {
    union { unsigned int i; float f; } x; x.i = ((unsigned int)u) << 16; return x.f;
}
__device__ __forceinline__ u16 f2bf(float f) {
    union { unsigned int i; float f; } x; x.f = f;
    unsigned int i = x.i;
    return (u16)((i + 0x7fffu + ((i >> 16) & 1u)) >> 16);   // RNE
}
__device__ __forceinline__ uint4 pack8(const float* __restrict__ src) {
    float4 f0 = *(const float4*)(src);
    float4 f1 = *(const float4*)(src + 4);
    union { u16 u[8]; uint4 v; } P;
    P.u[0] = f2bf(f0.x); P.u[1] = f2bf(f0.y); P.u[2] = f2bf(f0.z); P.u[3] = f2bf(f0.w);
    P.u[4] = f2bf(f1.x); P.u[5] = f2bf(f1.y); P.u[6] = f2bf(f1.z); P.u[7] = f2bf(f1.w);
    return P.v;
}

// async global->LDS, 16 B per lane; LDS dest = uniform base + lane*16.
__device__ __forceinline__ void gll16(void* lds, const void* g) {
    __builtin_amdgcn_global_load_lds(
        (const __attribute__((address_space(1))) unsigned int*)g,
        (__attribute__((address_space(3))) unsigned int*)lds, 16, 0, 0);
}

// ---------------------------------------------------------------------------
// Kernel 0: fp32 -> bf16 cast (memory-bound pre-pass).
// ---------------------------------------------------------------------------
__global__ __launch_bounds__(256) void cast_bf16(const float* __restrict__ src,
                                                 u16* __restrict__ dst, int n8) {
    int i = blockIdx.x * 256 + threadIdx.x;
    if (i < n8) *(uint4*)(dst + (size_t)i * 8) = pack8(src + (size_t)i * 8);
}

// ---------------------------------------------------------------------------
// Kernel 1: fused QKV projection + bias + RoPE + ReLU. bf16 inputs (pre-cast),
// global_load_lds width-16 staging, 128x128 tile, BK=32, 4 waves of 64x64.
// ---------------------------------------------------------------------------
__global__ __launch_bounds__(256) void gemm_qkv(
    const u16* __restrict__ Xb, const u16* __restrict__ Wqkvb,
    const float* __restrict__ bq, const float* __restrict__ bk, const float* __restrict__ bv,
    const float* __restrict__ cosT, const float* __restrict__ sinT,
    u16* __restrict__ Q, u16* __restrict__ K, u16* __restrict__ V)
{
    __shared__ __align__(16) u16 As[128 * 32];
    __shared__ __align__(16) u16 Bs[128 * 32];

    int t  = threadIdx.x;
    int bm = blockIdx.x;          // 0..63
    int bn = blockIdx.y;          // 0..47
    int region = bn >> 4;         // 0=q 1=k 2=v
    const u16*   W    = Wqkvb + (size_t)region * 4194304;
    const float* bias = (region == 0) ? bq : (region == 1 ? bk : bv);
    u16* OUT          = (region == 0) ? Q  : (region == 1 ? K  : V);

    int m0 = bm * 128;
    int n0 = (bn & 15) * 128;

    int w = t >> 6, lane = t & 63, quad = lane >> 4, l16 = lane & 15;
    int wm0 = (w >> 1) * 64, wn0 = (w & 1) * 64;
    int w32 = w * 32;
    int lr  = lane >> 2;          // 0..15 row in 16-row group
    int lc  = (lane & 3) * 8;     // col element

    const u16* ga = Xb + (size_t)(m0 + w32 + lr) * 2048 + lc;
    const u16* gb = W  + (size_t)(n0 + w32 + lr) * 2048 + lc;

    f32x4 acc[4][4] = {};

    for (int k0 = 0; k0 < 2048; k0 += 32) {
        __syncthreads();
        gll16(As + (size_t)w32 * 32,        ga + k0);
        gll16(As + (size_t)(w32 + 16) * 32, ga + k0 + 16 * 2048);
        gll16(Bs + (size_t)w32 * 32,        gb + k0);
        gll16(Bs + (size_t)(w32 + 16) * 32, gb + k0 + 16 * 2048);
        __syncthreads();

        bf16x8 af[4], bfr[4];
#pragma unroll
        for (int i = 0; i < 4; i++) af[i]  = *(const bf16x8*)(As + (wm0 + i * 16 + l16) * 32 + quad * 8);
#pragma unroll
        for (int j = 0; j < 4; j++) bfr[j] = *(const bf16x8*)(Bs + (wn0 + j * 16 + l16) * 32 + quad * 8);
#pragma unroll
        for (int i = 0; i < 4; i++)
#pragma unroll
            for (int j = 0; j < 4; j++)
                acc[i][j] = __builtin_amdgcn_mfma_f32_16x16x32_bf16(af[i], bfr[j], acc[i][j], 0, 0, 0);
    }

    // Epilogue: bias, RoPE via shfl_xor(1) (col == lane&15), ReLU for q,k.
#pragma unroll
    for (int i = 0; i < 4; i++) {
#pragma unroll
        for (int j = 0; j < 4; j++) {
            int nc   = n0 + wn0 + j * 16 + l16;
            int h    = nc >> 7, dpos = nc & 127;
            float bia = bias[nc];
#pragma unroll
            for (int r = 0; r < 4; r++) {
                int mr = m0 + wm0 + i * 16 + quad * 4 + r;   // C/D: row = quad*4+reg
                int b  = mr >> 12, s = mr & 4095;
                float val = acc[i][j][r] + bia;
                if (region < 2) {
                    float pair = __shfl_xor(val, 1, 64);
                    float c  = cosT[s * 128 + dpos];
                    float sn = sinT[s * 128 + dpos];
                    val = fmaxf(val * c + ((dpos & 1) ? pair : -pair) * sn, 0.f);
                }
                OUT[((size_t)(b * 16 + h) * 4096 + s) * 128 + dpos] = f2bf(val);
            }
        }
    }
}

// ---------------------------------------------------------------------------
// Kernel 2: vk partials (unchanged from R2). Per (b,h), 8 S-chunks of 512.
// ---------------------------------------------------------------------------
__global__ __launch_bounds__(256) void vk_partial(
    const u16* __restrict__ Kb, const u16* __restrict__ Vb, float* __restrict__ part)
{
    int bh = blockIdx.x;
    int sp = blockIdx.y;
    int t  = threadIdx.x;
    int tn = t >> 4, td = t & 15;
    int n0 = tn * 8, d0 = td * 8;
    const u16* Kp = Kb + (size_t)bh * 4096 * 128;
    const u16* Vp = Vb + (size_t)bh * 4096 * 128;
    int s0 = sp * 512;

    __shared__ __align__(16) u16 ks[8 * 128];
    __shared__ __align__(16) u16 vs[8 * 128];

    float acc[8][8] = {};
    float ksum[8] = {};

    for (int sc = 0; sc < 512; sc += 8) {
        __syncthreads();
        {
            int tt   = t & 127;
            int row  = tt >> 4;
            int cole = (tt & 15) * 8;
            const u16* srcp = (t < 128) ? Kp : Vp;
            u16*       dstp = (t < 128) ? ks : vs;
            const u16* src = srcp + (size_t)(s0 + sc + row) * 128 + cole;
            *(uint4*)((char*)dstp + tt * 16) = *(const uint4*)src;
        }
        __syncthreads();
#pragma unroll
        for (int ss = 0; ss < 8; ss++) {
            float vv[8], kv[8];
#pragma unroll
            for (int j = 0; j < 8; j++) vv[j] = bf2f(vs[ss * 128 + n0 + j]);
#pragma unroll
            for (int j = 0; j < 8; j++) kv[j] = bf2f(ks[ss * 128 + d0 + j]);
#pragma unroll
            for (int i = 0; i < 8; i++)
#pragma unroll
                for (int j = 0; j < 8; j++) acc[i][j] += vv[i] * kv[j];
            if (tn == 0) {
#pragma unroll
                for (int j = 0; j < 8; j++) ksum[j] += kv[j];
            }
        }
    }

    float* dst = part + (size_t)(bh * 8 + sp) * 16512;
#pragma unroll
    for (int i = 0; i < 8; i++)
#pragma unroll
        for (int j = 0; j < 8; j++) dst[(n0 + i) * 128 + d0 + j] = acc[i][j];
    if (tn == 0) {
#pragma unroll
        for (int j = 0; j < 8; j++) dst[16384 + d0 + j] = ksum[j];
    }
}

// ---------------------------------------------------------------------------
// Kernel 3: reduce 8 partials -> vkf[32][129*128] fp32.
// ---------------------------------------------------------------------------
__global__ __launch_bounds__(256) void vk_reduce(const float* __restrict__ part,
                                                 float* __restrict__ vkf)
{
    int bh = blockIdx.x;
    int by = blockIdx.y;
    int t  = threadIdx.x;
    int end = (by + 1) * 2064;
    for (int idx = by * 2064 + t; idx < end; idx += 256) {
        float s = 0.f;
#pragma unroll
        for (int p = 0; p < 8; p++) s += part[(size_t)(bh * 8 + p) * 16512 + idx];
        vkf[(size_t)bh * 16512 + idx] = s;
    }
}

// ---------------------------------------------------------------------------
// Kernel 4: denominators. rden[bh][s] = 1/(ksum . q[s] + 1e-15).
// ---------------------------------------------------------------------------
__global__ __launch_bounds__(256) void den_kernel(
    const u16* __restrict__ Qb, const float* __restrict__ vkf, float* __restrict__ rden)
{
    int bh = blockIdx.x, sb = blockIdx.y;
    __shared__ float ksumL[128];
    int t = threadIdx.x;
    if (t < 128) ksumL[t] = vkf[(size_t)bh * 16512 + 16384 + t];
    __syncthreads();
    int srow = t >> 1, half = t & 1;
    const u16*  q   = Qb + ((size_t)bh * 4096 + sb * 128 + srow) * 128 + half * 64;
    const float* kp = ksumL + half * 64;
    float p = 0.f;
#pragma unroll 8
    for (int d = 0; d < 64; d += 4) {
        ushort4 qv = *(const ushort4*)(q + d);
        p += bf2f(qv.x) * kp[d] + bf2f(qv.y) * kp[d + 1]
           + bf2f(qv.z) * kp[d + 2] + bf2f(qv.w) * kp[d + 3];
    }
    p += __shfl_xor(p, 1, 64);
    if (half == 0) rden[(size_t)bh * 4096 + sb * 128 + srow] = 1.0f / (p + 1e-15f);
}

// ---------------------------------------------------------------------------
// Kernel 5: hs via MFMA. Per (bh, sc): hs[128s,128n] = q[128,128] @ vk[128,128]^T,
// scaled by rden. LDS rows padded 128->136 elements (row stride 272 B) to break
// the same-bank quad pattern of stride-256 rows.
// ---------------------------------------------------------------------------
__global__ __launch_bounds__(256) void hs_mfma(
    const u16* __restrict__ Qb, const float* __restrict__ vkf,
    const float* __restrict__ rden, u16* __restrict__ HS)
{
    int bh = blockIdx.x, sc = blockIdx.y;
    __shared__ __align__(16) u16 qL[128 * 136];
    __shared__ __align__(16) u16 vkL[128 * 136];
    __shared__ float rdL[128];
    int t = threadIdx.x;

    const u16*   Qp   = Qb + ((size_t)bh * 4096 + sc * 128) * 128;
    const float* vsrc = vkf + (size_t)bh * 16512;
    int row = t >> 4, colc = (t & 15) * 8;
#pragma unroll
    for (int r8 = 0; r8 < 8; r8++) {
        int rr = row + r8 * 16;
        *(uint4*)(qL  + rr * 136 + colc) = *(const uint4*)(Qp + (size_t)rr * 128 + colc);
        *(uint4*)(vkL + rr * 136 + colc) = pack8(vsrc + (size_t)rr * 128 + colc);
    }
    if (t < 128) rdL[t] = rden[(size_t)bh * 4096 + sc * 128 + t];
    __syncthreads();

    int w = t >> 6, lane = t & 63, quad = lane >> 4, l16 = lane & 15;
    int wm0 = (w >> 1) * 64, wn0 = (w & 1) * 64;
    f32x4 acc[4][4] = {};
#pragma unroll
    for (int ks = 0; ks < 4; ks++) {
        bf16x8 af[4], bfr[4];
#pragma unroll
        for (int i = 0; i < 4; i++) af[i]  = *(const bf16x8*)(qL  + (wm0 + i * 16 + l16) * 136 + ks * 32 + quad * 8);
#pragma unroll
        for (int j = 0; j < 4; j++) bfr[j] = *(const bf16x8*)(vkL + (wn0 + j * 16 + l16) * 136 + ks * 32 + quad * 8);
#pragma unroll
        for (int i = 0; i < 4; i++)
#pragma unroll
            for (int j = 0; j < 4; j++)
                acc[i][j] = __builtin_amdgcn_mfma_f32_16x16x32_bf16(af[i], bfr[j], acc[i][j], 0, 0, 0);
    }

    int b = bh >> 4, h = bh & 15;
#pragma unroll
    for (int i = 0; i < 4; i++) {
#pragma unroll
        for (int j = 0; j < 4; j++) {
#pragma unroll
            for (int r = 0; r < 4; r++) {
                int sl = wm0 + i * 16 + quad * 4 + r;
                int n  = wn0 + j * 16 + l16;
                size_t srow = (size_t)b * 4096 + sc * 128 + sl;
                HS[srow * 2048 + h * 128 + n] = f2bf(acc[i][j][r] * rdL[sl]);
            }
        }
    }
}

// ---------------------------------------------------------------------------
// Kernel 6: out = HS @ Wo^T + bo (bf16 MFMA, global_load_lds staging), fp32 out.
// ---------------------------------------------------------------------------
__global__ __launch_bounds__(256) void gemm_out(
    const u16* __restrict__ HSm, const u16* __restrict__ Wob,
    const float* __restrict__ bo, float* __restrict__ OUT)
{
    __shared__ __align__(16) u16 As[128 * 32];
    __shared__ __align__(16) u16 Bs[128 * 32];

    int t  = threadIdx.x;
    int m0 = blockIdx.x * 128;
    int n0 = blockIdx.y * 128;

    int w = t >> 6, lane = t & 63, quad = lane >> 4, l16 = lane & 15;
    int wm0 = (w >> 1) * 64, wn0 = (w & 1) * 64;
    int w32 = w * 32;
    int lr  = lane >> 2;
    int lc  = (lane & 3) * 8;

    const u16* ga = HSm + (size_t)(m0 + w32 + lr) * 2048 + lc;
    const u16* gb = Wob + (size_t)(n0 + w32 + lr) * 2048 + lc;

    f32x4 acc[4][4] = {};

    for (int k0 = 0; k0 < 2048; k0 += 32) {
        __syncthreads();
        gll16(As + (size_t)w32 * 32,        ga + k0);
        gll16(As + (size_t)(w32 + 16) * 32, ga + k0 + 16 * 2048);
        gll16(Bs + (size_t)w32 * 32,        gb + k0);
        gll16(Bs + (size_t)(w32 + 16) * 32, gb + k0 + 16 * 2048);
        __syncthreads();

        bf16x8 af[4], bfr[4];
#pragma unroll
        for (int i = 0; i < 4; i++) af[i]  = *(const bf16x8*)(As + (wm0 + i * 16 + l16) * 32 + quad * 8);
#pragma unroll
        for (int j = 0; j < 4; j++) bfr[j] = *(const bf16x8*)(Bs + (wn0 + j * 16 + l16) * 32 + quad * 8);
#pragma unroll
        for (int i = 0; i < 4; i++)
#pragma unroll
            for (int j = 0; j < 4; j++)
                acc[i][j] = __builtin_amdgcn_mfma_f32_16x16x32_bf16(af[i], bfr[j], acc[i][j], 0, 0, 0);
    }

#pragma unroll
    for (int i = 0; i < 4; i++) {
#pragma unroll
        for (int j = 0; j < 4; j++) {
            int nc = n0 + wn0 + j * 16 + l16;
            float bia = bo[nc];
#pragma unroll
            for (int r = 0; r < 4; r++) {
                int mr = m0 + wm0 + i * 16 + quad * 4 + r;
                OUT[(size_t)mr * 2048 + nc] = acc[i][j][r] + bia;
            }
        }
    }
}

// ---------------------------------------------------------------------------
extern "C" void kernel_launch(void* const* d_in, const int* in_sizes, int n_in,
                              void* d_out, int out_size, void* d_ws, size_t ws_size,
                              hipStream_t stream) {
    const float* x    = (const float*)d_in[0];
    const float* cosT = (const float*)d_in[1];
    const float* sinT = (const float*)d_in[2];
    const float* Wq   = (const float*)d_in[3];
    const float* bq   = (const float*)d_in[4];
    const float* Wk   = (const float*)d_in[5];
    const float* bk   = (const float*)d_in[6];
    const float* Wv   = (const float*)d_in[7];
    const float* bv   = (const float*)d_in[8];
    const float* Wo   = (const float*)d_in[9];
    const float* bo   = (const float*)d_in[10];

    char* ws = (char*)d_ws;
    u16*   Wqkvb = (u16*)(ws);                   // 25,165,824 B  [3][2048][2048] bf16
    u16*   Wob   = (u16*)(ws + 25165824);        //  8,388,608 B
    u16*   Xb    = (u16*)(ws + 33554432);        // 33,554,432 B  (dead after gemm_qkv)
    float* part  = (float*)(ws + 33554432);      // alias Xb: 16,908,288 B
    u16*   V     = (u16*)(ws + 67108864);        // 33,554,432 B
    u16*   HS    = V;                            // V dead after vk_partial
    float* vkf   = (float*)(ws + 100663296);     //  2,113,536 B
    float* rden  = (float*)(ws + 102776832);     //    524,288 B  -> total ~103.3 MB

    // Q, K scratch in d_out (67,108,864 B); both dead before gemm_out writes it.
    u16* Q  = (u16*)d_out;
    u16* Kb = (u16*)d_out + 16777216;

    cast_bf16<<<8192, 256, 0, stream>>>(x,  Xb, 2097152);
    cast_bf16<<<2048, 256, 0, stream>>>(Wq, Wqkvb,           524288);
    cast_bf16<<<2048, 256, 0, stream>>>(Wk, Wqkvb + 4194304, 524288);
    cast_bf16<<<2048, 256, 0, stream>>>(Wv, Wqkvb + 8388608, 524288);
    cast_bf16<<<2048, 256, 0, stream>>>(Wo, Wob, 524288);

    gemm_qkv<<<dim3(64, 48), 256, 0, stream>>>(Xb, Wqkvb, bq, bk, bv, cosT, sinT, Q, Kb, V);
    vk_partial<<<dim3(32, 8), 256, 0, stream>>>(Kb, V, part);
    vk_reduce<<<dim3(32, 8), 256, 0, stream>>>(part, vkf);
    den_kernel<<<dim3(32, 32), 256, 0, stream>>>(Q, vkf, rden);
    hs_mfma<<<dim3(32, 32), 256, 0, stream>>>(Q, vkf, rden, HS);
    gemm_out<<<dim3(64, 16), 256, 0, stream>>>(HS, Wob, bo, (float*)d_out);
}

// Round 4
// 587.321 us; speedup vs baseline: 1.7910x; 1.1382x over previous
//
#include <hip/hip_runtime.h>

// LinearTransformerBlock on MI355X — R4.
// R3: 668 µs. gemm_qkv 295 µs (699 TF, MfmaUtil 31). Tail ~280 µs in VALU-bound
// vk_partial + 5 casts + den. R4: vk via MFMA (LDS-transposed operands, swizzled),
// single cast launch, den fused into hs_mfma, BK=64 two-panel GEMMs (halve
// barrier drains; LDS stays 32 KB so occupancy holds, unlike BK=128/m132).

typedef unsigned short u16;
typedef __attribute__((ext_vector_type(8))) short bf16x8;
typedef __attribute__((ext_vector_type(4))) float f32x4;

__device__ __forceinline__ float bf2f(u16 u) {
    union { unsigned int i; float f; } x; x.i = ((unsigned int)u) << 16; return x.f;
}
__device__ __forceinline__ u16 f2bf(float f) {
    union { unsigned int i; float f; } x; x.f = f;
    unsigned int i = x.i;
    return (u16)((i + 0x7fffu + ((i >> 16) & 1u)) >> 16);   // RNE
}
__device__ __forceinline__ uint4 pack8(const float* __restrict__ src) {
    float4 f0 = *(const float4*)(src);
    float4 f1 = *(const float4*)(src + 4);
    union { u16 u[8]; uint4 v; } P;
    P.u[0] = f2bf(f0.x); P.u[1] = f2bf(f0.y); P.u[2] = f2bf(f0.z); P.u[3] = f2bf(f0.w);
    P.u[4] = f2bf(f1.x); P.u[5] = f2bf(f1.y); P.u[6] = f2bf(f1.z); P.u[7] = f2bf(f1.w);
    return P.v;
}
__device__ __forceinline__ void gll16(void* lds, const void* g) {
    __builtin_amdgcn_global_load_lds(
        (const __attribute__((address_space(1))) unsigned int*)g,
        (__attribute__((address_space(3))) unsigned int*)lds, 16, 0, 0);
}

// ---------------------------------------------------------------------------
// Kernel 0: one-launch fp32 -> bf16 cast of X, Wq, Wk, Wv, Wo.
// Blocks: [0,8192) X ; then 4 x 2048 for the weights.
// ---------------------------------------------------------------------------
__global__ __launch_bounds__(256) void cast_all(
    const float* __restrict__ x,  const float* __restrict__ Wq,
    const float* __restrict__ Wk, const float* __restrict__ Wv,
    const float* __restrict__ Wo,
    u16* __restrict__ Xb, u16* __restrict__ Wqkvb, u16* __restrict__ Wob)
{
    int bid = blockIdx.x, t = threadIdx.x;
    const float* s; u16* d; size_t i;
    if (bid < 8192)       { s = x;  d = Xb;              i = (size_t)bid * 256 + t; }
    else if (bid < 10240) { s = Wq; d = Wqkvb;           i = (size_t)(bid - 8192)  * 256 + t; }
    else if (bid < 12288) { s = Wk; d = Wqkvb + 4194304; i = (size_t)(bid - 10240) * 256 + t; }
    else if (bid < 14336) { s = Wv; d = Wqkvb + 8388608; i = (size_t)(bid - 12288) * 256 + t; }
    else                  { s = Wo; d = Wob;             i = (size_t)(bid - 14336) * 256 + t; }
    *(uint4*)(d + i * 8) = pack8(s + i * 8);
}

// ---------------------------------------------------------------------------
// Kernel 1: QKV projection + bias + RoPE + ReLU. BK=64 two-panel staging
// (panel layout keeps LDS row stride 64 B == BK32 bank profile).
// ---------------------------------------------------------------------------
__global__ __launch_bounds__(256) void gemm_qkv(
    const u16* __restrict__ Xb, const u16* __restrict__ Wqkvb,
    const float* __restrict__ bq, const float* __restrict__ bk, const float* __restrict__ bv,
    const float* __restrict__ cosT, const float* __restrict__ sinT,
    u16* __restrict__ Q, u16* __restrict__ K, u16* __restrict__ V)
{
    __shared__ __align__(16) u16 As[2 * 128 * 32];
    __shared__ __align__(16) u16 Bs[2 * 128 * 32];

    int t  = threadIdx.x;
    int bm = blockIdx.x;          // 0..63
    int bn = blockIdx.y;          // 0..47
    int region = bn >> 4;
    const u16*   W    = Wqkvb + (size_t)region * 4194304;
    const float* bias = (region == 0) ? bq : (region == 1 ? bk : bv);
    u16* OUT          = (region == 0) ? Q  : (region == 1 ? K  : V);

    int m0 = bm * 128;
    int n0 = (bn & 15) * 128;

    int w = t >> 6, lane = t & 63, quad = lane >> 4, l16 = lane & 15;
    int wm0 = (w >> 1) * 64, wn0 = (w & 1) * 64;
    int w32 = w * 32;
    int lr  = lane >> 2;
    int lc  = (lane & 3) * 8;

    const u16* ga = Xb + (size_t)(m0 + w32 + lr) * 2048 + lc;
    const u16* gb = W  + (size_t)(n0 + w32 + lr) * 2048 + lc;

    f32x4 acc[4][4] = {};

    for (int k0 = 0; k0 < 2048; k0 += 64) {
        __syncthreads();
#pragma unroll
        for (int p = 0; p < 2; p++) {
            gll16(As + p * 4096 + (size_t)w32 * 32,        ga + k0 + p * 32);
            gll16(As + p * 4096 + (size_t)(w32 + 16) * 32, ga + k0 + p * 32 + 16 * 2048);
            gll16(Bs + p * 4096 + (size_t)w32 * 32,        gb + k0 + p * 32);
            gll16(Bs + p * 4096 + (size_t)(w32 + 16) * 32, gb + k0 + p * 32 + 16 * 2048);
        }
        __syncthreads();

#pragma unroll
        for (int kk = 0; kk < 2; kk++) {
            bf16x8 af[4], bfr[4];
#pragma unroll
            for (int i = 0; i < 4; i++) af[i]  = *(const bf16x8*)(As + kk * 4096 + (wm0 + i * 16 + l16) * 32 + quad * 8);
#pragma unroll
            for (int j = 0; j < 4; j++) bfr[j] = *(const bf16x8*)(Bs + kk * 4096 + (wn0 + j * 16 + l16) * 32 + quad * 8);
#pragma unroll
            for (int i = 0; i < 4; i++)
#pragma unroll
                for (int j = 0; j < 4; j++)
                    acc[i][j] = __builtin_amdgcn_mfma_f32_16x16x32_bf16(af[i], bfr[j], acc[i][j], 0, 0, 0);
        }
    }

#pragma unroll
    for (int i = 0; i < 4; i++) {
#pragma unroll
        for (int j = 0; j < 4; j++) {
            int nc   = n0 + wn0 + j * 16 + l16;
            int h    = nc >> 7, dpos = nc & 127;
            float bia = bias[nc];
#pragma unroll
            for (int r = 0; r < 4; r++) {
                int mr = m0 + wm0 + i * 16 + quad * 4 + r;
                int b  = mr >> 12, s = mr & 4095;
                float val = acc[i][j][r] + bia;
                if (region < 2) {
                    float pair = __shfl_xor(val, 1, 64);
                    float c  = cosT[s * 128 + dpos];
                    float sn = sinT[s * 128 + dpos];
                    val = fmaxf(val * c + ((dpos & 1) ? pair : -pair) * sn, 0.f);
                }
                OUT[((size_t)(b * 16 + h) * 4096 + s) * 128 + dpos] = f2bf(val);
            }
        }
    }
}

// ---------------------------------------------------------------------------
// Kernel 2: ksum[bh][d] = sum_s K[bh][s][d]  (atomic partial per 512-s block).
// ---------------------------------------------------------------------------
__global__ __launch_bounds__(256) void ksum_kernel(
    const u16* __restrict__ Kb, float* __restrict__ ksumbuf)
{
    int bh = blockIdx.x, sc8 = blockIdx.y, t = threadIdx.x;
    int dpair = (t & 63) * 2, sq = t >> 6;
    const u16* base = Kb + (size_t)bh * 524288 + (size_t)(sc8 * 512 + sq * 128) * 128 + dpair;
    float s0 = 0.f, s1 = 0.f;
#pragma unroll 8
    for (int r = 0; r < 128; r++) {
        unsigned int wv = *(const unsigned int*)(base + (size_t)r * 128);
        s0 += bf2f((u16)(wv & 0xffff));
        s1 += bf2f((u16)(wv >> 16));
    }
    __shared__ float red[4][128];
    red[sq][dpair]     = s0;
    red[sq][dpair + 1] = s1;
    __syncthreads();
    if (t < 128) {
        float tot = red[0][t] + red[1][t] + red[2][t] + red[3][t];
        atomicAdd(&ksumbuf[bh * 128 + t], tot);
    }
}

// ---------------------------------------------------------------------------
// Kernel 3: vk partials via MFMA. Per (bh, sk): C[128n][128d] = sum_s V[s,n]K[s,d]
// over 512 s. Operands staged transposed into LDS ([row][32 s], swizzled so
// frag reads stay contiguous-16B: elem = r*32 + (((s>>3)+(r>>3))&3)*8 + (s&7)).
// ---------------------------------------------------------------------------
__device__ __forceinline__ int vkswz(int r, int s) {
    return r * 32 + (((( s >> 3) + (r >> 3)) & 3) << 3) + (s & 7);
}

__global__ __launch_bounds__(256) void vk_mfma(
    const u16* __restrict__ Kb, const u16* __restrict__ Vb, float* __restrict__ part)
{
    int bh = blockIdx.x;          // 0..31
    int sk = blockIdx.y;          // 0..7
    int t  = threadIdx.x;
    int s0 = sk * 512;

    __shared__ __align__(16) u16 Kt[128 * 32];
    __shared__ __align__(16) u16 Vt[128 * 32];

    const u16* Kp = Kb + (size_t)bh * 524288;
    const u16* Vp = Vb + (size_t)bh * 524288;

    int dgrp  = t & 15;           // 16 lanes cover 128 cols
    int d0    = dgrp * 8;
    int spair = (t >> 4) * 2;     // 0..30
    int sg    = spair >> 3;

    int w = t >> 6, lane = t & 63, quad = lane >> 4, l16 = lane & 15;
    int nbase = (w >> 1) * 64, dbase = (w & 1) * 64;

    f32x4 acc[4][4] = {};

    for (int tile = 0; tile < 16; tile++) {
        int st = s0 + tile * 32;
        __syncthreads();
        {
            const u16* kg = Kp + (size_t)(st + spair) * 128 + d0;
            const u16* vg = Vp + (size_t)(st + spair) * 128 + d0;
            union { uint4 v; u16 u[8]; } ka, kb, va, vb;
            ka.v = *(const uint4*)kg;  kb.v = *(const uint4*)(kg + 128);
            va.v = *(const uint4*)vg;  vb.v = *(const uint4*)(vg + 128);
            int swz = (((sg + dgrp) & 3) << 3) + (spair & 7);
#pragma unroll
            for (int i = 0; i < 8; i++) {
                int e = (d0 + i) * 32 + swz;
                *(unsigned int*)(Kt + e) = (unsigned int)ka.u[i] | ((unsigned int)kb.u[i] << 16);
                *(unsigned int*)(Vt + e) = (unsigned int)va.u[i] | ((unsigned int)vb.u[i] << 16);
            }
        }
        __syncthreads();

        bf16x8 af[4], bfr[4];
#pragma unroll
        for (int i = 0; i < 4; i++) {
            int r = nbase + i * 16 + l16;
            af[i] = *(const bf16x8*)(Vt + r * 32 + (((quad + (r >> 3)) & 3) << 3));
        }
#pragma unroll
        for (int j = 0; j < 4; j++) {
            int r = dbase + j * 16 + l16;
            bfr[j] = *(const bf16x8*)(Kt + r * 32 + (((quad + (r >> 3)) & 3) << 3));
        }
#pragma unroll
        for (int i = 0; i < 4; i++)
#pragma unroll
            for (int j = 0; j < 4; j++)
                acc[i][j] = __builtin_amdgcn_mfma_f32_16x16x32_bf16(af[i], bfr[j], acc[i][j], 0, 0, 0);
    }

    float* dst = part + (size_t)(bh * 8 + sk) * 16384;
#pragma unroll
    for (int i = 0; i < 4; i++) {
#pragma unroll
        for (int j = 0; j < 4; j++) {
#pragma unroll
            for (int r = 0; r < 4; r++) {
                int n = nbase + i * 16 + quad * 4 + r;   // C/D row
                int d = dbase + j * 16 + l16;            // C/D col
                dst[n * 128 + d] = acc[i][j][r];
            }
        }
    }
}

// ---------------------------------------------------------------------------
// Kernel 4: reduce 8 partials -> vkf[32][128*128] fp32.
// ---------------------------------------------------------------------------
__global__ __launch_bounds__(256) void vk_reduce(const float* __restrict__ part,
                                                 float* __restrict__ vkf)
{
    int bh = blockIdx.x, by = blockIdx.y, t = threadIdx.x;
    int end = (by + 1) * 2048;
    for (int idx = by * 2048 + t; idx < end; idx += 256) {
        float s = 0.f;
#pragma unroll
        for (int p = 0; p < 8; p++) s += part[(size_t)(bh * 8 + p) * 16384 + idx];
        vkf[(size_t)bh * 16384 + idx] = s;
    }
}

// ---------------------------------------------------------------------------
// Kernel 5: hs via MFMA, denominator fused. Per (bh, sc):
// hs[128s,128n] = (q @ vk^T) * rden, rden = 1/(q . ksum + eps).
// ---------------------------------------------------------------------------
__global__ __launch_bounds__(256) void hs_mfma(
    const u16* __restrict__ Qb, const float* __restrict__ vkf,
    const float* __restrict__ ksumbuf, u16* __restrict__ HS)
{
    int bh = blockIdx.x, sc = blockIdx.y;
    __shared__ __align__(16) u16 qL[128 * 136];
    __shared__ __align__(16) u16 vkL[128 * 136];
    __shared__ float rdL[128];
    __shared__ float ksumL[128];
    int t = threadIdx.x;

    const u16*   Qp   = Qb + ((size_t)bh * 4096 + sc * 128) * 128;
    const float* vsrc = vkf + (size_t)bh * 16384;
    int row = t >> 4, colc = (t & 15) * 8;
#pragma unroll
    for (int r8 = 0; r8 < 8; r8++) {
        int rr = row + r8 * 16;
        *(uint4*)(qL  + rr * 136 + colc) = *(const uint4*)(Qp + (size_t)rr * 128 + colc);
        *(uint4*)(vkL + rr * 136 + colc) = pack8(vsrc + (size_t)rr * 128 + colc);
    }
    if (t < 128) ksumL[t] = ksumbuf[bh * 128 + t];
    __syncthreads();

    // Fused denominator: thread pair (srow, half).
    {
        int srow = t >> 1, half = t & 1;
        const u16*   q  = qL + srow * 136 + half * 64;
        const float* kp = ksumL + half * 64;
        float p = 0.f;
#pragma unroll 8
        for (int d = 0; d < 64; d += 4) {
            ushort4 qv = *(const ushort4*)(q + d);
            p += bf2f(qv.x) * kp[d] + bf2f(qv.y) * kp[d + 1]
               + bf2f(qv.z) * kp[d + 2] + bf2f(qv.w) * kp[d + 3];
        }
        p += __shfl_xor(p, 1, 64);
        if (half == 0) rdL[srow] = 1.0f / (p + 1e-15f);
    }

    int w = t >> 6, lane = t & 63, quad = lane >> 4, l16 = lane & 15;
    int wm0 = (w >> 1) * 64, wn0 = (w & 1) * 64;
    f32x4 acc[4][4] = {};
#pragma unroll
    for (int ks = 0; ks < 4; ks++) {
        bf16x8 af[4], bfr[4];
#pragma unroll
        for (int i = 0; i < 4; i++) af[i]  = *(const bf16x8*)(qL  + (wm0 + i * 16 + l16) * 136 + ks * 32 + quad * 8);
#pragma unroll
        for (int j = 0; j < 4; j++) bfr[j] = *(const bf16x8*)(vkL + (wn0 + j * 16 + l16) * 136 + ks * 32 + quad * 8);
#pragma unroll
        for (int i = 0; i < 4; i++)
#pragma unroll
            for (int j = 0; j < 4; j++)
                acc[i][j] = __builtin_amdgcn_mfma_f32_16x16x32_bf16(af[i], bfr[j], acc[i][j], 0, 0, 0);
    }
    __syncthreads();   // rdL ready for cross-thread reads

    int b = bh >> 4, h = bh & 15;
#pragma unroll
    for (int i = 0; i < 4; i++) {
#pragma unroll
        for (int j = 0; j < 4; j++) {
#pragma unroll
            for (int r = 0; r < 4; r++) {
                int sl = wm0 + i * 16 + quad * 4 + r;
                int n  = wn0 + j * 16 + l16;
                size_t srow = (size_t)b * 4096 + sc * 128 + sl;
                HS[srow * 2048 + h * 128 + n] = f2bf(acc[i][j][r] * rdL[sl]);
            }
        }
    }
}

// ---------------------------------------------------------------------------
// Kernel 6: out = HS @ Wo^T + bo, BK=64 two-panel, fp32 out.
// ---------------------------------------------------------------------------
__global__ __launch_bounds__(256) void gemm_out(
    const u16* __restrict__ HSm, const u16* __restrict__ Wob,
    const float* __restrict__ bo, float* __restrict__ OUT)
{
    __shared__ __align__(16) u16 As[2 * 128 * 32];
    __shared__ __align__(16) u16 Bs[2 * 128 * 32];

    int t  = threadIdx.x;
    int m0 = blockIdx.x * 128;
    int n0 = blockIdx.y * 128;

    int w = t >> 6, lane = t & 63, quad = lane >> 4, l16 = lane & 15;
    int wm0 = (w >> 1) * 64, wn0 = (w & 1) * 64;
    int w32 = w * 32;
    int lr  = lane >> 2;
    int lc  = (lane & 3) * 8;

    const u16* ga = HSm + (size_t)(m0 + w32 + lr) * 2048 + lc;
    const u16* gb = Wob + (size_t)(n0 + w32 + lr) * 2048 + lc;

    f32x4 acc[4][4] = {};

    for (int k0 = 0; k0 < 2048; k0 += 64) {
        __syncthreads();
#pragma unroll
        for (int p = 0; p < 2; p++) {
            gll16(As + p * 4096 + (size_t)w32 * 32,        ga + k0 + p * 32);
            gll16(As + p * 4096 + (size_t)(w32 + 16) * 32, ga + k0 + p * 32 + 16 * 2048);
            gll16(Bs + p * 4096 + (size_t)w32 * 32,        gb + k0 + p * 32);
            gll16(Bs + p * 4096 + (size_t)(w32 + 16) * 32, gb + k0 + p * 32 + 16 * 2048);
        }
        __syncthreads();

#pragma unroll
        for (int kk = 0; kk < 2; kk++) {
            bf16x8 af[4], bfr[4];
#pragma unroll
            for (int i = 0; i < 4; i++) af[i]  = *(const bf16x8*)(As + kk * 4096 + (wm0 + i * 16 + l16) * 32 + quad * 8);
#pragma unroll
            for (int j = 0; j < 4; j++) bfr[j] = *(const bf16x8*)(Bs + kk * 4096 + (wn0 + j * 16 + l16) * 32 + quad * 8);
#pragma unroll
            for (int i = 0; i < 4; i++)
#pragma unroll
                for (int j = 0; j < 4; j++)
                    acc[i][j] = __builtin_amdgcn_mfma_f32_16x16x32_bf16(af[i], bfr[j], acc[i][j], 0, 0, 0);
        }
    }

#pragma unroll
    for (int i = 0; i < 4; i++) {
#pragma unroll
        for (int j = 0; j < 4; j++) {
            int nc = n0 + wn0 + j * 16 + l16;
            float bia = bo[nc];
#pragma unroll
            for (int r = 0; r < 4; r++) {
                int mr = m0 + wm0 + i * 16 + quad * 4 + r;
                OUT[(size_t)mr * 2048 + nc] = acc[i][j][r] + bia;
            }
        }
    }
}

// ---------------------------------------------------------------------------
extern "C" void kernel_launch(void* const* d_in, const int* in_sizes, int n_in,
                              void* d_out, int out_size, void* d_ws, size_t ws_size,
                              hipStream_t stream) {
    const float* x    = (const float*)d_in[0];
    const float* cosT = (const float*)d_in[1];
    const float* sinT = (const float*)d_in[2];
    const float* Wq   = (const float*)d_in[3];
    const float* bq   = (const float*)d_in[4];
    const float* Wk   = (const float*)d_in[5];
    const float* bk   = (const float*)d_in[6];
    const float* Wv   = (const float*)d_in[7];
    const float* bv   = (const float*)d_in[8];
    const float* Wo   = (const float*)d_in[9];
    const float* bo   = (const float*)d_in[10];

    char* ws = (char*)d_ws;
    u16*   Wqkvb   = (u16*)(ws);                 // 25,165,824 B
    u16*   Wob     = (u16*)(ws + 25165824);      //  8,388,608 B
    u16*   Xb      = (u16*)(ws + 33554432);      // 33,554,432 B (dead after gemm_qkv)
    float* part    = (float*)(ws + 33554432);    // alias Xb: 16,777,216 B
    u16*   V       = (u16*)(ws + 67108864);      // 33,554,432 B
    u16*   HS      = V;                          // V dead after vk_mfma
    float* vkf     = (float*)(ws + 100663296);   //  2,097,152 B
    float* ksumbuf = (float*)(ws + 102760448);   //     16,384 B -> ~102.8 MB total

    // Q, K scratch in d_out (exactly 67,108,864 B); dead before gemm_out writes.
    u16* Q  = (u16*)d_out;
    u16* Kb = (u16*)d_out + 16777216;

    hipMemsetAsync(ksumbuf, 0, 32 * 128 * sizeof(float), stream);
    cast_all<<<16384, 256, 0, stream>>>(x, Wq, Wk, Wv, Wo, Xb, Wqkvb, Wob);
    gemm_qkv<<<dim3(64, 48), 256, 0, stream>>>(Xb, Wqkvb, bq, bk, bv, cosT, sinT, Q, Kb, V);
    ksum_kernel<<<dim3(32, 8), 256, 0, stream>>>(Kb, ksumbuf);
    vk_mfma<<<dim3(32, 8), 256, 0, stream>>>(Kb, V, part);
    vk_reduce<<<dim3(32, 8), 256, 0, stream>>>(part, vkf);
    hs_mfma<<<dim3(32, 32), 256, 0, stream>>>(Q, vkf, ksumbuf, HS);
    gemm_out<<<dim3(64, 16), 256, 0, stream>>>(HS, Wob, bo, (float*)d_out);
}

// Round 5
// 573.955 us; speedup vs baseline: 1.8327x; 1.0233x over previous
//
#include <hip/hip_runtime.h>

// LinearTransformerBlock on MI355X — R5.
// R4 post-mortem: BK=64 REGRESSED gemm_qkv (295->332 µs, Occ 33->22.5, m132
// lesson: K-tile size trades occupancy at net loss on the m97 structure).
// R5: revert both GEMMs to BK=32 (known-good); vk_reduce emits bf16 so
// hs_mfma drops pack8 + halves vk bytes. Keep R4's vk-MFMA chain, single
// cast, fused denominator, Q/K scratch in d_out.

typedef unsigned short u16;
typedef __attribute__((ext_vector_type(8))) short bf16x8;
typedef __attribute__((ext_vector_type(4))) float f32x4;

__device__ __forceinline__ float bf2f(u16 u) {
    union { unsigned int i; float f; } x; x.i = ((unsigned int)u) << 16; return x.f;
}
__device__ __forceinline__ u16 f2bf(float f) {
    union { unsigned int i; float f; } x; x.f = f;
    unsigned int i = x.i;
    return (u16)((i + 0x7fffu + ((i >> 16) & 1u)) >> 16);   // RNE
}
__device__ __forceinline__ uint4 pack8(const float* __restrict__ src) {
    float4 f0 = *(const float4*)(src);
    float4 f1 = *(const float4*)(src + 4);
    union { u16 u[8]; uint4 v; } P;
    P.u[0] = f2bf(f0.x); P.u[1] = f2bf(f0.y); P.u[2] = f2bf(f0.z); P.u[3] = f2bf(f0.w);
    P.u[4] = f2bf(f1.x); P.u[5] = f2bf(f1.y); P.u[6] = f2bf(f1.z); P.u[7] = f2bf(f1.w);
    return P.v;
}
__device__ __forceinline__ void gll16(void* lds, const void* g) {
    __builtin_amdgcn_global_load_lds(
        (const __attribute__((address_space(1))) unsigned int*)g,
        (__attribute__((address_space(3))) unsigned int*)lds, 16, 0, 0);
}

// ---------------------------------------------------------------------------
// Kernel 0: one-launch fp32 -> bf16 cast of X, Wq, Wk, Wv, Wo.
// ---------------------------------------------------------------------------
__global__ __launch_bounds__(256) void cast_all(
    const float* __restrict__ x,  const float* __restrict__ Wq,
    const float* __restrict__ Wk, const float* __restrict__ Wv,
    const float* __restrict__ Wo,
    u16* __restrict__ Xb, u16* __restrict__ Wqkvb, u16* __restrict__ Wob)
{
    int bid = blockIdx.x, t = threadIdx.x;
    const float* s; u16* d; size_t i;
    if (bid < 8192)       { s = x;  d = Xb;              i = (size_t)bid * 256 + t; }
    else if (bid < 10240) { s = Wq; d = Wqkvb;           i = (size_t)(bid - 8192)  * 256 + t; }
    else if (bid < 12288) { s = Wk; d = Wqkvb + 4194304; i = (size_t)(bid - 10240) * 256 + t; }
    else if (bid < 14336) { s = Wv; d = Wqkvb + 8388608; i = (size_t)(bid - 12288) * 256 + t; }
    else                  { s = Wo; d = Wob;             i = (size_t)(bid - 14336) * 256 + t; }
    *(uint4*)(d + i * 8) = pack8(s + i * 8);
}

// ---------------------------------------------------------------------------
// Kernel 1: QKV projection + bias + RoPE + ReLU. BK=32 (reverted: best occ).
// ---------------------------------------------------------------------------
__global__ __launch_bounds__(256) void gemm_qkv(
    const u16* __restrict__ Xb, const u16* __restrict__ Wqkvb,
    const float* __restrict__ bq, const float* __restrict__ bk, const float* __restrict__ bv,
    const float* __restrict__ cosT, const float* __restrict__ sinT,
    u16* __restrict__ Q, u16* __restrict__ K, u16* __restrict__ V)
{
    __shared__ __align__(16) u16 As[128 * 32];
    __shared__ __align__(16) u16 Bs[128 * 32];

    int t  = threadIdx.x;
    int bm = blockIdx.x;          // 0..63
    int bn = blockIdx.y;          // 0..47
    int region = bn >> 4;
    const u16*   W    = Wqkvb + (size_t)region * 4194304;
    const float* bias = (region == 0) ? bq : (region == 1 ? bk : bv);
    u16* OUT          = (region == 0) ? Q  : (region == 1 ? K  : V);

    int m0 = bm * 128;
    int n0 = (bn & 15) * 128;

    int w = t >> 6, lane = t & 63, quad = lane >> 4, l16 = lane & 15;
    int wm0 = (w >> 1) * 64, wn0 = (w & 1) * 64;
    int w32 = w * 32;
    int lr  = lane >> 2;
    int lc  = (lane & 3) * 8;

    const u16* ga = Xb + (size_t)(m0 + w32 + lr) * 2048 + lc;
    const u16* gb = W  + (size_t)(n0 + w32 + lr) * 2048 + lc;

    f32x4 acc[4][4] = {};

    for (int k0 = 0; k0 < 2048; k0 += 32) {
        __syncthreads();
        gll16(As + (size_t)w32 * 32,        ga + k0);
        gll16(As + (size_t)(w32 + 16) * 32, ga + k0 + 16 * 2048);
        gll16(Bs + (size_t)w32 * 32,        gb + k0);
        gll16(Bs + (size_t)(w32 + 16) * 32, gb + k0 + 16 * 2048);
        __syncthreads();

        bf16x8 af[4], bfr[4];
#pragma unroll
        for (int i = 0; i < 4; i++) af[i]  = *(const bf16x8*)(As + (wm0 + i * 16 + l16) * 32 + quad * 8);
#pragma unroll
        for (int j = 0; j < 4; j++) bfr[j] = *(const bf16x8*)(Bs + (wn0 + j * 16 + l16) * 32 + quad * 8);
#pragma unroll
        for (int i = 0; i < 4; i++)
#pragma unroll
            for (int j = 0; j < 4; j++)
                acc[i][j] = __builtin_amdgcn_mfma_f32_16x16x32_bf16(af[i], bfr[j], acc[i][j], 0, 0, 0);
    }

#pragma unroll
    for (int i = 0; i < 4; i++) {
#pragma unroll
        for (int j = 0; j < 4; j++) {
            int nc   = n0 + wn0 + j * 16 + l16;
            int h    = nc >> 7, dpos = nc & 127;
            float bia = bias[nc];
#pragma unroll
            for (int r = 0; r < 4; r++) {
                int mr = m0 + wm0 + i * 16 + quad * 4 + r;   // C/D: row = quad*4+reg
                int b  = mr >> 12, s = mr & 4095;
                float val = acc[i][j][r] + bia;
                if (region < 2) {
                    float pair = __shfl_xor(val, 1, 64);
                    float c  = cosT[s * 128 + dpos];
                    float sn = sinT[s * 128 + dpos];
                    val = fmaxf(val * c + ((dpos & 1) ? pair : -pair) * sn, 0.f);
                }
                OUT[((size_t)(b * 16 + h) * 4096 + s) * 128 + dpos] = f2bf(val);
            }
        }
    }
}

// ---------------------------------------------------------------------------
// Kernel 2: ksum[bh][d] = sum_s K[bh][s][d]  (atomic partial per 512-s block).
// ---------------------------------------------------------------------------
__global__ __launch_bounds__(256) void ksum_kernel(
    const u16* __restrict__ Kb, float* __restrict__ ksumbuf)
{
    int bh = blockIdx.x, sc8 = blockIdx.y, t = threadIdx.x;
    int dpair = (t & 63) * 2, sq = t >> 6;
    const u16* base = Kb + (size_t)bh * 524288 + (size_t)(sc8 * 512 + sq * 128) * 128 + dpair;
    float s0 = 0.f, s1 = 0.f;
#pragma unroll 8
    for (int r = 0; r < 128; r++) {
        unsigned int wv = *(const unsigned int*)(base + (size_t)r * 128);
        s0 += bf2f((u16)(wv & 0xffff));
        s1 += bf2f((u16)(wv >> 16));
    }
    __shared__ float red[4][128];
    red[sq][dpair]     = s0;
    red[sq][dpair + 1] = s1;
    __syncthreads();
    if (t < 128) {
        float tot = red[0][t] + red[1][t] + red[2][t] + red[3][t];
        atomicAdd(&ksumbuf[bh * 128 + t], tot);
    }
}

// ---------------------------------------------------------------------------
// Kernel 3: vk partials via MFMA. Per (bh, sk): C[128n][128d] = sum_s V[s,n]K[s,d]
// over 512 s. Operands staged transposed into LDS (swizzled).
// ---------------------------------------------------------------------------
__global__ __launch_bounds__(256) void vk_mfma(
    const u16* __restrict__ Kb, const u16* __restrict__ Vb, float* __restrict__ part)
{
    int bh = blockIdx.x;          // 0..31
    int sk = blockIdx.y;          // 0..7
    int t  = threadIdx.x;
    int s0 = sk * 512;

    __shared__ __align__(16) u16 Kt[128 * 32];
    __shared__ __align__(16) u16 Vt[128 * 32];

    const u16* Kp = Kb + (size_t)bh * 524288;
    const u16* Vp = Vb + (size_t)bh * 524288;

    int dgrp  = t & 15;
    int d0    = dgrp * 8;
    int spair = (t >> 4) * 2;
    int sg    = spair >> 3;

    int w = t >> 6, lane = t & 63, quad = lane >> 4, l16 = lane & 15;
    int nbase = (w >> 1) * 64, dbase = (w & 1) * 64;

    f32x4 acc[4][4] = {};

    for (int tile = 0; tile < 16; tile++) {
        int st = s0 + tile * 32;
        __syncthreads();
        {
            const u16* kg = Kp + (size_t)(st + spair) * 128 + d0;
            const u16* vg = Vp + (size_t)(st + spair) * 128 + d0;
            union { uint4 v; u16 u[8]; } ka, kb, va, vb;
            ka.v = *(const uint4*)kg;  kb.v = *(const uint4*)(kg + 128);
            va.v = *(const uint4*)vg;  vb.v = *(const uint4*)(vg + 128);
            int swz = (((sg + dgrp) & 3) << 3) + (spair & 7);
#pragma unroll
            for (int i = 0; i < 8; i++) {
                int e = (d0 + i) * 32 + swz;
                *(unsigned int*)(Kt + e) = (unsigned int)ka.u[i] | ((unsigned int)kb.u[i] << 16);
                *(unsigned int*)(Vt + e) = (unsigned int)va.u[i] | ((unsigned int)vb.u[i] << 16);
            }
        }
        __syncthreads();

        bf16x8 af[4], bfr[4];
#pragma unroll
        for (int i = 0; i < 4; i++) {
            int r = nbase + i * 16 + l16;
            af[i] = *(const bf16x8*)(Vt + r * 32 + (((quad + (r >> 3)) & 3) << 3));
        }
#pragma unroll
        for (int j = 0; j < 4; j++) {
            int r = dbase + j * 16 + l16;
            bfr[j] = *(const bf16x8*)(Kt + r * 32 + (((quad + (r >> 3)) & 3) << 3));
        }
#pragma unroll
        for (int i = 0; i < 4; i++)
#pragma unroll
            for (int j = 0; j < 4; j++)
                acc[i][j] = __builtin_amdgcn_mfma_f32_16x16x32_bf16(af[i], bfr[j], acc[i][j], 0, 0, 0);
    }

    float* dst = part + (size_t)(bh * 8 + sk) * 16384;
#pragma unroll
    for (int i = 0; i < 4; i++) {
#pragma unroll
        for (int j = 0; j < 4; j++) {
#pragma unroll
            for (int r = 0; r < 4; r++) {
                int n = nbase + i * 16 + quad * 4 + r;
                int d = dbase + j * 16 + l16;
                dst[n * 128 + d] = acc[i][j][r];
            }
        }
    }
}

// ---------------------------------------------------------------------------
// Kernel 4: reduce 8 partials -> vkb[32][128*128] bf16 (hs consumes bf16).
// ---------------------------------------------------------------------------
__global__ __launch_bounds__(256) void vk_reduce(const float* __restrict__ part,
                                                 u16* __restrict__ vkb)
{
    int bh = blockIdx.x, by = blockIdx.y, t = threadIdx.x;
    int end = (by + 1) * 2048;
    for (int idx = by * 2048 + t; idx < end; idx += 256) {
        float s = 0.f;
#pragma unroll
        for (int p = 0; p < 8; p++) s += part[(size_t)(bh * 8 + p) * 16384 + idx];
        vkb[(size_t)bh * 16384 + idx] = f2bf(s);
    }
}

// ---------------------------------------------------------------------------
// Kernel 5: hs via MFMA, denominator fused. Per (bh, sc):
// hs[128s,128n] = (q @ vk^T) * rden, rden = 1/(q . ksum + eps). vk is bf16.
// ---------------------------------------------------------------------------
__global__ __launch_bounds__(256) void hs_mfma(
    const u16* __restrict__ Qb, const u16* __restrict__ vkb,
    const float* __restrict__ ksumbuf, u16* __restrict__ HS)
{
    int bh = blockIdx.x, sc = blockIdx.y;
    __shared__ __align__(16) u16 qL[128 * 136];
    __shared__ __align__(16) u16 vkL[128 * 136];
    __shared__ float rdL[128];
    __shared__ float ksumL[128];
    int t = threadIdx.x;

    const u16* Qp   = Qb  + ((size_t)bh * 4096 + sc * 128) * 128;
    const u16* vsrc = vkb + (size_t)bh * 16384;
    int row = t >> 4, colc = (t & 15) * 8;
#pragma unroll
    for (int r8 = 0; r8 < 8; r8++) {
        int rr = row + r8 * 16;
        *(uint4*)(qL  + rr * 136 + colc) = *(const uint4*)(Qp   + (size_t)rr * 128 + colc);
        *(uint4*)(vkL + rr * 136 + colc) = *(const uint4*)(vsrc + (size_t)rr * 128 + colc);
    }
    if (t < 128) ksumL[t] = ksumbuf[bh * 128 + t];
    __syncthreads();

    // Fused denominator: thread pair (srow, half).
    {
        int srow = t >> 1, half = t & 1;
        const u16*   q  = qL + srow * 136 + half * 64;
        const float* kp = ksumL + half * 64;
        float p = 0.f;
#pragma unroll 8
        for (int d = 0; d < 64; d += 4) {
            ushort4 qv = *(const ushort4*)(q + d);
            p += bf2f(qv.x) * kp[d] + bf2f(qv.y) * kp[d + 1]
               + bf2f(qv.z) * kp[d + 2] + bf2f(qv.w) * kp[d + 3];
        }
        p += __shfl_xor(p, 1, 64);
        if (half == 0) rdL[srow] = 1.0f / (p + 1e-15f);
    }

    int w = t >> 6, lane = t & 63, quad = lane >> 4, l16 = lane & 15;
    int wm0 = (w >> 1) * 64, wn0 = (w & 1) * 64;
    f32x4 acc[4][4] = {};
#pragma unroll
    for (int ks = 0; ks < 4; ks++) {
        bf16x8 af[4], bfr[4];
#pragma unroll
        for (int i = 0; i < 4; i++) af[i]  = *(const bf16x8*)(qL  + (wm0 + i * 16 + l16) * 136 + ks * 32 + quad * 8);
#pragma unroll
        for (int j = 0; j < 4; j++) bfr[j] = *(const bf16x8*)(vkL + (wn0 + j * 16 + l16) * 136 + ks * 32 + quad * 8);
#pragma unroll
        for (int i = 0; i < 4; i++)
#pragma unroll
            for (int j = 0; j < 4; j++)
                acc[i][j] = __builtin_amdgcn_mfma_f32_16x16x32_bf16(af[i], bfr[j], acc[i][j], 0, 0, 0);
    }
    __syncthreads();   // rdL ready

    int b = bh >> 4, h = bh & 15;
#pragma unroll
    for (int i = 0; i < 4; i++) {
#pragma unroll
        for (int j = 0; j < 4; j++) {
#pragma unroll
            for (int r = 0; r < 4; r++) {
                int sl = wm0 + i * 16 + quad * 4 + r;
                int n  = wn0 + j * 16 + l16;
                size_t srow = (size_t)b * 4096 + sc * 128 + sl;
                HS[srow * 2048 + h * 128 + n] = f2bf(acc[i][j][r] * rdL[sl]);
            }
        }
    }
}

// ---------------------------------------------------------------------------
// Kernel 6: out = HS @ Wo^T + bo, BK=32 (reverted), fp32 out.
// ---------------------------------------------------------------------------
__global__ __launch_bounds__(256) void gemm_out(
    const u16* __restrict__ HSm, const u16* __restrict__ Wob,
    const float* __restrict__ bo, float* __restrict__ OUT)
{
    __shared__ __align__(16) u16 As[128 * 32];
    __shared__ __align__(16) u16 Bs[128 * 32];

    int t  = threadIdx.x;
    int m0 = blockIdx.x * 128;
    int n0 = blockIdx.y * 128;

    int w = t >> 6, lane = t & 63, quad = lane >> 4, l16 = lane & 15;
    int wm0 = (w >> 1) * 64, wn0 = (w & 1) * 64;
    int w32 = w * 32;
    int lr  = lane >> 2;
    int lc  = (lane & 3) * 8;

    const u16* ga = HSm + (size_t)(m0 + w32 + lr) * 2048 + lc;
    const u16* gb = Wob + (size_t)(n0 + w32 + lr) * 2048 + lc;

    f32x4 acc[4][4] = {};

    for (int k0 = 0; k0 < 2048; k0 += 32) {
        __syncthreads();
        gll16(As + (size_t)w32 * 32,        ga + k0);
        gll16(As + (size_t)(w32 + 16) * 32, ga + k0 + 16 * 2048);
        gll16(Bs + (size_t)w32 * 32,        gb + k0);
        gll16(Bs + (size_t)(w32 + 16) * 32, gb + k0 + 16 * 2048);
        __syncthreads();

        bf16x8 af[4], bfr[4];
#pragma unroll
        for (int i = 0; i < 4; i++) af[i]  = *(const bf16x8*)(As + (wm0 + i * 16 + l16) * 32 + quad * 8);
#pragma unroll
        for (int j = 0; j < 4; j++) bfr[j] = *(const bf16x8*)(Bs + (wn0 + j * 16 + l16) * 32 + quad * 8);
#pragma unroll
        for (int i = 0; i < 4; i++)
#pragma unroll
            for (int j = 0; j < 4; j++)
                acc[i][j] = __builtin_amdgcn_mfma_f32_16x16x32_bf16(af[i], bfr[j], acc[i][j], 0, 0, 0);
    }

#pragma unroll
    for (int i = 0; i < 4; i++) {
#pragma unroll
        for (int j = 0; j < 4; j++) {
            int nc = n0 + wn0 + j * 16 + l16;
            float bia = bo[nc];
#pragma unroll
            for (int r = 0; r < 4; r++) {
                int mr = m0 + wm0 + i * 16 + quad * 4 + r;
                OUT[(size_t)mr * 2048 + nc] = acc[i][j][r] + bia;
            }
        }
    }
}

// ---------------------------------------------------------------------------
extern "C" void kernel_launch(void* const* d_in, const int* in_sizes, int n_in,
                              void* d_out, int out_size, void* d_ws, size_t ws_size,
                              hipStream_t stream) {
    const float* x    = (const float*)d_in[0];
    const float* cosT = (const float*)d_in[1];
    const float* sinT = (const float*)d_in[2];
    const float* Wq   = (const float*)d_in[3];
    const float* bq   = (const float*)d_in[4];
    const float* Wk   = (const float*)d_in[5];
    const float* bk   = (const float*)d_in[6];
    const float* Wv   = (const float*)d_in[7];
    const float* bv   = (const float*)d_in[8];
    const float* Wo   = (const float*)d_in[9];
    const float* bo   = (const float*)d_in[10];

    char* ws = (char*)d_ws;
    u16*   Wqkvb   = (u16*)(ws);                 // 25,165,824 B
    u16*   Wob     = (u16*)(ws + 25165824);      //  8,388,608 B
    u16*   Xb      = (u16*)(ws + 33554432);      // 33,554,432 B (dead after gemm_qkv)
    float* part    = (float*)(ws + 33554432);    // alias Xb: 16,777,216 B
    u16*   V       = (u16*)(ws + 67108864);      // 33,554,432 B
    u16*   HS      = V;                          // V dead after vk_mfma
    u16*   vkb     = (u16*)(ws + 100663296);     //  1,048,576 B (bf16)
    float* ksumbuf = (float*)(ws + 101711872);   //     16,384 B -> ~101.7 MB total

    // Q, K scratch in d_out (exactly 67,108,864 B); dead before gemm_out writes.
    u16* Q  = (u16*)d_out;
    u16* Kb = (u16*)d_out + 16777216;

    hipMemsetAsync(ksumbuf, 0, 32 * 128 * sizeof(float), stream);
    cast_all<<<16384, 256, 0, stream>>>(x, Wq, Wk, Wv, Wo, Xb, Wqkvb, Wob);
    gemm_qkv<<<dim3(64, 48), 256, 0, stream>>>(Xb, Wqkvb, bq, bk, bv, cosT, sinT, Q, Kb, V);
    ksum_kernel<<<dim3(32, 8), 256, 0, stream>>>(Kb, ksumbuf);
    vk_mfma<<<dim3(32, 8), 256, 0, stream>>>(Kb, V, part);
    vk_reduce<<<dim3(32, 8), 256, 0, stream>>>(part, vkb);
    hs_mfma<<<dim3(32, 32), 256, 0, stream>>>(Q, vkb, ksumbuf, HS);
    gemm_out<<<dim3(64, 16), 256, 0, stream>>>(HS, Wob, bo, (float*)d_out);
}